// Round 17
// baseline (252.507 us; speedup 1.0000x reference)
//
#include <hip/hip_runtime.h>

#define PH 512
#define PW 512
#define PLANE (PH * PW)

enum { M_F0 = 0, M_MID = 1, M_MONLY = 2, M_LAST = 3 };

// ---- compile-time Gaussian weights (literal constants in the ISA) ---------
constexpr double cexp_pos(double z) {
  double term = 1.0, sum = 1.0;
  for (int k = 1; k < 160; ++k) {
    term *= z / (double)k;
    sum += term;
  }
  return sum;
}
template <int LVL, int R>
struct WTab {
  float w[2 * R + 1];
  constexpr WTab() : w{} {
    double sig = 1.0;
    for (int i = 0; i < LVL; ++i) sig *= 2.0;
    double g[2 * R + 1] = {};
    double s = 0.0;
    for (int t = 0; t <= 2 * R; ++t) {
      double x = (double)(t - R);
      g[t] = 1.0 / cexp_pos((x * x) / (2.0 * sig * sig));
      s += g[t];
    }
    for (int t = 0; t <= 2 * R; ++t) w[t] = (float)(g[t] / s);
  }
};

__device__ __forceinline__ int clampi(int v, int hi) {
  return v < 0 ? 0 : (v > hi ? hi : v);
}
__device__ __forceinline__ int swz(int bid, int nwg) {
  const int q = nwg >> 3;
  return (bid & 7) * q + (bid >> 3);
}
union HU { ushort u; _Float16 h; };
union BU { uint4 q; ushort u[8]; };
__device__ __forceinline__ float h2f(ushort s) {
  HU x; x.u = s; return (float)x.h;
}
__device__ __forceinline__ ushort f2h(float f) {
  HU x; x.h = (_Float16)f; return x.u;
}
__device__ __forceinline__ void q2f8(uint4 q, float* v) {
  BU b; b.q = q;
#pragma unroll
  for (int j = 0; j < 8; ++j) v[j] = h2f(b.u[j]);
}
__device__ __forceinline__ void sth8(ushort* __restrict__ p, const float* v) {
  BU b;
#pragma unroll
  for (int j = 0; j < 8; ++j) b.u[j] = f2h(v[j]);
  *(uint4*)p = b.q;
}
__device__ __forceinline__ void ff2f8(float4 a, float4 b, float* v) {
  v[0] = a.x; v[1] = a.y; v[2] = a.z; v[3] = a.w;
  v[4] = b.x; v[5] = b.y; v[6] = b.z; v[7] = b.w;
}
__device__ __forceinline__ void stf8(float* __restrict__ p, const float* v) {
  *(float4*)p = make_float4(v[0], v[1], v[2], v[3]);
  *(float4*)(p + 4) = make_float4(v[4], v[5], v[6], v[7]);
}

// ---------------- fused per-level kernel, 64x64 tile, single LDS buffer ----
// R17 = R12 (the 216 us empirical optimum) + compiler fence in the in-place
// H-conv (forbids the ds_write hoisting that raced in R14; aliasing is
// row-local = intra-wave, so the fence alone is sufficient). D is saved from
// the window center between barriers (R12 scheme); epilogue prefetch holds
// only qacc/qm/qm4 (resp. i0/m for F0) to keep VGPR ~40 (R16's qd pushed 60).
template <int LVL, int R, int MODE>
__global__ __launch_bounds__(512) void fused_lvl(
    const ushort* __restrict__ Sc, const ushort* __restrict__ Smk,
    const ushort* __restrict__ Gm4p, const float* __restrict__ in0,
    const float* __restrict__ in1, const float* __restrict__ inm,
    ushort* __restrict__ oS, ushort* __restrict__ oM,
    ushort* __restrict__ accP, float* __restrict__ outp, int cn3) {
  constexpr WTab<LVL, R> WT;
  constexpr int R8 = ((R + 7) / 8) * 8; // 8,16,24,24
  constexpr int WW = 64 + 2 * R8;       // 80,96,112,112
  constexpr int WSTR = WW + 6;          // b64 ops; 4-way H-read is structural
  constexpr int VWIN = 64 + 2 * R;      // 76,84,100,108
  constexpr int NCH = WW / 8;
  constexpr int NJOBS = VWIN * NCH;
  constexpr int NHJ = VWIN * 8;
  __shared__ float Wb[VWIN * WSTR];

  const int bid = swz(blockIdx.x, gridDim.x);
  const int tid = threadIdx.x;
  const int p = bid >> 6, t = bid & 63;
  const int tx = t & 7;
  const int x0 = tx << 6, y0 = (t >> 3) << 6;
  const bool edge = (tx == 0) || (tx == 7);
  const int ey = tid >> 3, exq = (tid & 7) << 3;
  const size_t erow = (size_t)(y0 + ey) * PW + x0 + exq;

  const bool ismask = (MODE == M_MONLY) || (MODE != M_LAST && p >= cn3);
  const int pm = ismask ? ((MODE == M_MONLY) ? p : p - cn3) : 0;
  const int n = p / 3;

  // ---- T14 prefetch of pointwise epilogue streams (issued before staging)
  uint4 qacc{}, qm{}, qm4{};
  float4 fi0a{}, fi0b{}, fmka{}, fmkb{};
  if (!ismask) {
    if (MODE == M_F0) {
      const float* p0 = in0 + (size_t)p * PLANE + erow;
      fi0a = ((const float4*)p0)[0];
      fi0b = ((const float4*)p0)[1];
      const float* pk = inm + (size_t)n * PLANE + erow;
      fmka = ((const float4*)pk)[0];
      fmkb = ((const float4*)pk)[1];
    } else {
      qacc = *(const uint4*)(accP + (size_t)p * PLANE + erow);
      qm = *(const uint4*)(Smk + (size_t)n * PLANE + erow);
      if (MODE == M_LAST)
        qm4 = *(const uint4*)(Gm4p + (size_t)n * PLANE + erow);
    }
  }

  // ---- fill Wb: job = (row, ch8); rows y-clamped, cols x-clamped ----
  for (int j0 = tid; j0 < NJOBS; j0 += 512) {
    const int row = j0 / NCH, ch = j0 % NCH;
    const int gy = clampi(y0 + row - R, PH - 1);
    const int gx = x0 - R8 + (ch << 3);
    float v[8];
    if (MODE == M_F0) {
      if (!ismask) {
        const float* r0 = in0 + (size_t)p * PLANE + (size_t)gy * PW;
        const float* r1 = in1 + (size_t)p * PLANE + (size_t)gy * PW;
        if (!edge || (gx >= 0 && gx <= PW - 8)) {
          float a[8], bb[8];
          ff2f8(((const float4*)(r0 + gx))[0], ((const float4*)(r0 + gx))[1], a);
          ff2f8(((const float4*)(r1 + gx))[0], ((const float4*)(r1 + gx))[1], bb);
#pragma unroll
          for (int j = 0; j < 8; ++j) v[j] = bb[j] - a[j];
        } else {
#pragma unroll
          for (int j = 0; j < 8; ++j) {
            const int cx = clampi(gx + j, PW - 1);
            v[j] = r1[cx] - r0[cx];
          }
        }
      } else {
        const float* rm = inm + (size_t)pm * PLANE + (size_t)gy * PW;
        if (!edge || (gx >= 0 && gx <= PW - 8)) {
          ff2f8(((const float4*)(rm + gx))[0], ((const float4*)(rm + gx))[1], v);
        } else {
#pragma unroll
          for (int j = 0; j < 8; ++j) v[j] = rm[clampi(gx + j, PW - 1)];
        }
      }
    } else {
      const ushort* sp =
          (ismask ? Smk + (size_t)pm * PLANE : Sc + (size_t)p * PLANE) +
          (size_t)gy * PW;
      if (!edge || (gx >= 0 && gx <= PW - 8)) {
        q2f8(*(const uint4*)&sp[gx], v);
      } else {
#pragma unroll
        for (int j = 0; j < 8; ++j) v[j] = h2f(sp[clampi(gx + j, PW - 1)]);
      }
    }
    float* d = &Wb[row * WSTR + (ch << 3)];
#pragma unroll
    for (int k = 0; k < 4; ++k)
      *(float2*)&d[2 * k] = make_float2(v[2 * k], v[2 * k + 1]);
  }
  __syncthreads();

  // ---- save D (window center at output pixels) before H overwrites it ----
  float D[8];
  if (!ismask) {
    const float* dp = &Wb[(R + ey) * WSTR + R8 + exq];
#pragma unroll
    for (int k = 0; k < 4; ++k) {
      const float2 dv = *(const float2*)(dp + 2 * k);
      D[2 * k] = dv.x;
      D[2 * k + 1] = dv.y;
    }
  }
  __syncthreads();

  // ---- H conv IN PLACE: job (r,cg) reads row r window, writes cols cg*8 ----
  // Aliasing is row-local (one wave); fence stops compiler hoisting writes.
#pragma unroll
  for (int i = 0; i < (NHJ + 511) / 512; ++i) {
    const int j0 = tid + (i << 9);
    if (j0 < NHJ) {
      const int r = j0 >> 3, cg = j0 & 7;
      constexpr int basep = R8 - R;
      const float* wr = &Wb[r * WSTR + basep + (cg << 3)];
      float a[8];
#pragma unroll
      for (int i2 = 0; i2 < 8; ++i2) a[i2] = 0.f;
#pragma unroll
      for (int j2 = 0; j2 < R + 4; ++j2) {
        const float2 v2 = *(const float2*)&wr[2 * j2];
        const int j0e = 2 * j2, j1e = 2 * j2 + 1;
#pragma unroll
        for (int i2 = 0; i2 < 8; ++i2) {
          if (i2 <= j0e && j0e - i2 <= 2 * R)
            a[i2] = fmaf(WT.w[j0e - i2], v2.x, a[i2]);
          if (i2 <= j1e && j1e - i2 <= 2 * R)
            a[i2] = fmaf(WT.w[j1e - i2], v2.y, a[i2]);
        }
      }
      asm volatile("" ::: "memory"); // all reads before any in-place write
      float* hr = &Wb[r * WSTR + (cg << 3)];
#pragma unroll
      for (int k2 = 0; k2 < 4; ++k2)
        *(float2*)&hr[2 * k2] = make_float2(a[2 * k2], a[2 * k2 + 1]);
    }
  }
  __syncthreads();

  // ---- V conv: 8 consecutive rows at column `lane` ----
  const int lane = tid & 63, yg = tid >> 6;
  float b[8];
#pragma unroll
  for (int i = 0; i < 8; ++i) b[i] = 0.f;
#pragma unroll
  for (int j = 0; j < 2 * R + 8; ++j) {
    const float v = Wb[((yg << 3) + j) * WSTR + lane];
#pragma unroll
    for (int i = 0; i < 8; ++i)
      if (i <= j && j - i <= 2 * R) b[i] = fmaf(WT.w[j - i], v, b[i]);
  }
  __syncthreads(); // V reads done -> Wb reusable as transpose stash

#pragma unroll
  for (int i = 0; i < 8; ++i) Wb[lane * 65 + (yg << 3) + i] = b[i];
  __syncthreads();
  float bs[8];
#pragma unroll
  for (int j = 0; j < 8; ++j) bs[j] = Wb[(exq + j) * 65 + ey];

  if (ismask) {
    sth8(oM + (size_t)pm * PLANE + erow, bs);
    return;
  }

  if (MODE == M_F0) {
    float i0v[8], mv[8], av[8];
    ff2f8(fi0a, fi0b, i0v);
    ff2f8(fmka, fmkb, mv);
#pragma unroll
    for (int j = 0; j < 8; ++j) av[j] = i0v[j] + mv[j] * (D[j] - bs[j]);
    sth8(accP + (size_t)p * PLANE + erow, av);
    sth8(oS + (size_t)p * PLANE + erow, bs);
  } else if (MODE == M_MID) {
    float av[8], mv[8];
    q2f8(qacc, av);
    q2f8(qm, mv);
#pragma unroll
    for (int j = 0; j < 8; ++j) av[j] += mv[j] * (D[j] - bs[j]);
    sth8(accP + (size_t)p * PLANE + erow, av);
    sth8(oS + (size_t)p * PLANE + erow, bs);
  } else { // M_LAST: out = acc + Gm3*(D3 - D4) + Gm4*D4
    float av[8], m3[8], m4[8], o[8];
    q2f8(qacc, av);
    q2f8(qm, m3);
    q2f8(qm4, m4);
#pragma unroll
    for (int j = 0; j < 8; ++j)
      o[j] = av[j] + m3[j] * (D[j] - bs[j]) + m4[j] * bs[j];
    stf8(outp + (size_t)p * PLANE + erow, o);
  }
}

// ---------------- host -----------------------------------------------------
extern "C" void kernel_launch(void* const* d_in, const int* in_sizes, int n_in,
                              void* d_out, int out_size, void* d_ws,
                              size_t ws_size, hipStream_t stream) {
  const float* img0 = (const float*)d_in[0];
  const float* img1 = (const float*)d_in[1];
  const float* mask = (const float*)d_in[2];
  float* out = (float*)d_out;

  const int NTOT = 16;
  const size_t perImg = (size_t)11 * PLANE * sizeof(ushort);
  int CN = 16;
  while (CN > 1 && (size_t)CN * perImg > ws_size) CN >>= 1;

  for (int s = 0; s < NTOT; s += CN) {
    ushort* SA = (ushort*)d_ws; // [D:3CN][m:CN]
    ushort* SB = SA + (size_t)4 * CN * PLANE;
    ushort* acc = SB + (size_t)4 * CN * PLANE; // 3CN planes
    ushort* SAm = SA + (size_t)3 * CN * PLANE;
    ushort* SBm = SB + (size_t)3 * CN * PLANE;

    const float* in0 = img0 + (size_t)s * 3 * PLANE;
    const float* in1 = img1 + (size_t)s * 3 * PLANE;
    const float* inm = mask + (size_t)s * PLANE;
    float* o = out + (size_t)s * 3 * PLANE;

    const int cn3 = 3 * CN;
    const dim3 blk(512);
    const int gAll = 4 * CN * 64, gD = 3 * CN * 64, gM = CN * 64;
    const ushort* nb = nullptr;
    const float* nf = nullptr;

    // L0: acc = i0 + m*(D0-D1); SA.D = D1; SA.m = Gm1
    hipLaunchKernelGGL((fused_lvl<0, 6, M_F0>), dim3(gAll), blk, 0, stream, nb,
                       nb, nb, in0, in1, inm, SA, SAm, acc, (float*)nullptr,
                       cn3);
    // L1: acc += Gm1*(D1-D2); SB.D = D2; SB.m = Gm2
    hipLaunchKernelGGL((fused_lvl<1, 10, M_MID>), dim3(gAll), blk, 0, stream,
                       SA, SAm, nb, nf, nf, nf, SB, SBm, acc, (float*)nullptr,
                       cn3);
    // L2: acc += Gm2*(D2-D3); SA.D = D3; SA.m = Gm3
    hipLaunchKernelGGL((fused_lvl<2, 18, M_MID>), dim3(gAll), blk, 0, stream,
                       SB, SBm, nb, nf, nf, nf, SA, SAm, acc, (float*)nullptr,
                       cn3);
    // L3a: Gm4 = blur(Gm3) -> SB.m
    hipLaunchKernelGGL((fused_lvl<3, 22, M_MONLY>), dim3(gM), blk, 0, stream,
                       nb, SAm, nb, nf, nf, nf, (ushort*)nullptr, SBm,
                       (ushort*)nullptr, (float*)nullptr, cn3);
    // L3b: out = acc + Gm3*(D3-D4) + Gm4*D4
    hipLaunchKernelGGL((fused_lvl<3, 22, M_LAST>), dim3(gD), blk, 0, stream, SA,
                       SAm, SBm, nf, nf, nf, (ushort*)nullptr,
                       (ushort*)nullptr, acc, o, cn3);
  }
}

// Round 18
// 215.539 us; speedup vs baseline: 1.1715x; 1.1715x over previous
//
#include <hip/hip_runtime.h>

#define PH 512
#define PW 512
#define PLANE (PH * PW)

enum { M_F0 = 0, M_MID = 1, M_MONLY = 2, M_LAST = 3 };

// ---- compile-time Gaussian weights (literal constants in the ISA) ---------
constexpr double cexp_pos(double z) {
  double term = 1.0, sum = 1.0;
  for (int k = 1; k < 160; ++k) {
    term *= z / (double)k;
    sum += term;
  }
  return sum;
}
template <int LVL, int R>
struct WTab {
  float w[2 * R + 1];
  constexpr WTab() : w{} {
    double sig = 1.0;
    for (int i = 0; i < LVL; ++i) sig *= 2.0;
    double g[2 * R + 1] = {};
    double s = 0.0;
    for (int t = 0; t <= 2 * R; ++t) {
      double x = (double)(t - R);
      g[t] = 1.0 / cexp_pos((x * x) / (2.0 * sig * sig));
      s += g[t];
    }
    for (int t = 0; t <= 2 * R; ++t) w[t] = (float)(g[t] / s);
  }
};

__device__ __forceinline__ int clampi(int v, int hi) {
  return v < 0 ? 0 : (v > hi ? hi : v);
}
__device__ __forceinline__ int swz(int bid, int nwg) {
  const int q = nwg >> 3;
  return (bid & 7) * q + (bid >> 3);
}
union HU { ushort u; _Float16 h; };
union BU { uint4 q; ushort u[8]; };
__device__ __forceinline__ float h2f(ushort s) {
  HU x; x.u = s; return (float)x.h;
}
__device__ __forceinline__ ushort f2h(float f) {
  HU x; x.h = (_Float16)f; return x.u;
}
__device__ __forceinline__ void q2f8(uint4 q, float* v) {
  BU b; b.q = q;
#pragma unroll
  for (int j = 0; j < 8; ++j) v[j] = h2f(b.u[j]);
}
__device__ __forceinline__ void sth8(ushort* __restrict__ p, const float* v) {
  BU b;
#pragma unroll
  for (int j = 0; j < 8; ++j) b.u[j] = f2h(v[j]);
  *(uint4*)p = b.q;
}
__device__ __forceinline__ void ff2f8(float4 a, float4 b, float* v) {
  v[0] = a.x; v[1] = a.y; v[2] = a.z; v[3] = a.w;
  v[4] = b.x; v[5] = b.y; v[6] = b.z; v[7] = b.w;
}
__device__ __forceinline__ void stf8(float* __restrict__ p, const float* v) {
  *(float4*)p = make_float4(v[0], v[1], v[2], v[3]);
  *(float4*)(p + 4) = make_float4(v[4], v[5], v[6], v[7]);
}

// ---------------- fused per-level kernel, 64x64 tile, single LDS buffer ----
// R18 = R16 minus the fence = R12's in-place b64 H-conv loop byte-identical
// (the schedule that validated in R12/R13/R16), D-save phase deleted, D rides
// the epilogue global prefetch (qd; F0 prefetches in1 and forms D=i1-i0).
// One fewer barrier + one fewer LDS phase than R12; fewer held regs than R17.
template <int LVL, int R, int MODE>
__global__ __launch_bounds__(512) void fused_lvl(
    const ushort* __restrict__ Sc, const ushort* __restrict__ Smk,
    const ushort* __restrict__ Gm4p, const float* __restrict__ in0,
    const float* __restrict__ in1, const float* __restrict__ inm,
    ushort* __restrict__ oS, ushort* __restrict__ oM,
    ushort* __restrict__ accP, float* __restrict__ outp, int cn3) {
  constexpr WTab<LVL, R> WT;
  constexpr int R8 = ((R + 7) / 8) * 8; // 8,16,24,24
  constexpr int WW = 64 + 2 * R8;       // 80,96,112,112
  constexpr int WSTR = WW + 6;          // == 6 mod 8 -> b64 reads <=2-way
  constexpr int VWIN = 64 + 2 * R;      // 76,84,100,108
  constexpr int NCH = WW / 8;
  constexpr int NJOBS = VWIN * NCH;
  constexpr int NHJ = VWIN * 8;
  __shared__ float Wb[VWIN * WSTR];

  const int bid = swz(blockIdx.x, gridDim.x);
  const int tid = threadIdx.x;
  const int p = bid >> 6, t = bid & 63;
  const int tx = t & 7;
  const int x0 = tx << 6, y0 = (t >> 3) << 6;
  const bool edge = (tx == 0) || (tx == 7);
  const int ey = tid >> 3, exq = (tid & 7) << 3;
  const size_t erow = (size_t)(y0 + ey) * PW + x0 + exq;

  const bool ismask = (MODE == M_MONLY) || (MODE != M_LAST && p >= cn3);
  const int pm = ismask ? ((MODE == M_MONLY) ? p : p - cn3) : 0;
  const int n = p / 3;

  // ---- prefetch pointwise epilogue streams incl. the D source ----
  uint4 qacc{}, qm{}, qm4{}, qd{};
  float4 fi0a{}, fi0b{}, fi1a{}, fi1b{}, fmka{}, fmkb{};
  if (!ismask) {
    if (MODE == M_F0) {
      const float* p0 = in0 + (size_t)p * PLANE + erow;
      fi0a = ((const float4*)p0)[0];
      fi0b = ((const float4*)p0)[1];
      const float* p1 = in1 + (size_t)p * PLANE + erow;
      fi1a = ((const float4*)p1)[0];
      fi1b = ((const float4*)p1)[1];
      const float* pk = inm + (size_t)n * PLANE + erow;
      fmka = ((const float4*)pk)[0];
      fmkb = ((const float4*)pk)[1];
    } else {
      qacc = *(const uint4*)(accP + (size_t)p * PLANE + erow);
      qm = *(const uint4*)(Smk + (size_t)n * PLANE + erow);
      qd = *(const uint4*)(Sc + (size_t)p * PLANE + erow);
      if (MODE == M_LAST)
        qm4 = *(const uint4*)(Gm4p + (size_t)n * PLANE + erow);
    }
  }

  // ---- fill Wb: job = (row, ch8); rows y-clamped, cols x-clamped ----
  for (int j0 = tid; j0 < NJOBS; j0 += 512) {
    const int row = j0 / NCH, ch = j0 % NCH;
    const int gy = clampi(y0 + row - R, PH - 1);
    const int gx = x0 - R8 + (ch << 3);
    float v[8];
    if (MODE == M_F0) {
      if (!ismask) {
        const float* r0 = in0 + (size_t)p * PLANE + (size_t)gy * PW;
        const float* r1 = in1 + (size_t)p * PLANE + (size_t)gy * PW;
        if (!edge || (gx >= 0 && gx <= PW - 8)) {
          float a[8], bb[8];
          ff2f8(((const float4*)(r0 + gx))[0], ((const float4*)(r0 + gx))[1], a);
          ff2f8(((const float4*)(r1 + gx))[0], ((const float4*)(r1 + gx))[1], bb);
#pragma unroll
          for (int j = 0; j < 8; ++j) v[j] = bb[j] - a[j];
        } else {
#pragma unroll
          for (int j = 0; j < 8; ++j) {
            const int cx = clampi(gx + j, PW - 1);
            v[j] = r1[cx] - r0[cx];
          }
        }
      } else {
        const float* rm = inm + (size_t)pm * PLANE + (size_t)gy * PW;
        if (!edge || (gx >= 0 && gx <= PW - 8)) {
          ff2f8(((const float4*)(rm + gx))[0], ((const float4*)(rm + gx))[1], v);
        } else {
#pragma unroll
          for (int j = 0; j < 8; ++j) v[j] = rm[clampi(gx + j, PW - 1)];
        }
      }
    } else {
      const ushort* sp =
          (ismask ? Smk + (size_t)pm * PLANE : Sc + (size_t)p * PLANE) +
          (size_t)gy * PW;
      if (!edge || (gx >= 0 && gx <= PW - 8)) {
        q2f8(*(const uint4*)&sp[gx], v);
      } else {
#pragma unroll
        for (int j = 0; j < 8; ++j) v[j] = h2f(sp[clampi(gx + j, PW - 1)]);
      }
    }
    float* d = &Wb[row * WSTR + (ch << 3)];
#pragma unroll
    for (int k = 0; k < 4; ++k)
      *(float2*)&d[2 * k] = make_float2(v[2 * k], v[2 * k + 1]);
  }
  __syncthreads();

  // ---- H conv IN PLACE: job (r,cg) reads row r window, writes cols cg*8 ----
  // (identical loop body to R12/R13/R16 -> identical, validated schedule)
#pragma unroll
  for (int i = 0; i < (NHJ + 511) / 512; ++i) {
    const int j0 = tid + (i << 9);
    if (j0 < NHJ) {
      const int r = j0 >> 3, cg = j0 & 7;
      constexpr int basep = R8 - R;
      const float* wr = &Wb[r * WSTR + basep + (cg << 3)];
      float a[8];
#pragma unroll
      for (int i2 = 0; i2 < 8; ++i2) a[i2] = 0.f;
#pragma unroll
      for (int j2 = 0; j2 < R + 4; ++j2) {
        const float2 v2 = *(const float2*)&wr[2 * j2];
        const int j0e = 2 * j2, j1e = 2 * j2 + 1;
#pragma unroll
        for (int i2 = 0; i2 < 8; ++i2) {
          if (i2 <= j0e && j0e - i2 <= 2 * R)
            a[i2] = fmaf(WT.w[j0e - i2], v2.x, a[i2]);
          if (i2 <= j1e && j1e - i2 <= 2 * R)
            a[i2] = fmaf(WT.w[j1e - i2], v2.y, a[i2]);
        }
      }
      float* hr = &Wb[r * WSTR + (cg << 3)];
#pragma unroll
      for (int k2 = 0; k2 < 4; ++k2)
        *(float2*)&hr[2 * k2] = make_float2(a[2 * k2], a[2 * k2 + 1]);
    }
  }
  __syncthreads();

  // ---- V conv: 8 consecutive rows at column `lane` ----
  const int lane = tid & 63, yg = tid >> 6;
  float b[8];
#pragma unroll
  for (int i = 0; i < 8; ++i) b[i] = 0.f;
#pragma unroll
  for (int j = 0; j < 2 * R + 8; ++j) {
    const float v = Wb[((yg << 3) + j) * WSTR + lane];
#pragma unroll
    for (int i = 0; i < 8; ++i)
      if (i <= j && j - i <= 2 * R) b[i] = fmaf(WT.w[j - i], v, b[i]);
  }
  __syncthreads(); // V reads done -> Wb reusable as transpose stash

#pragma unroll
  for (int i = 0; i < 8; ++i) Wb[lane * 65 + (yg << 3) + i] = b[i];
  __syncthreads();
  float bs[8];
#pragma unroll
  for (int j = 0; j < 8; ++j) bs[j] = Wb[(exq + j) * 65 + ey];

  if (ismask) {
    sth8(oM + (size_t)pm * PLANE + erow, bs);
    return;
  }

  if (MODE == M_F0) {
    float i0v[8], i1v[8], mv[8], av[8];
    ff2f8(fi0a, fi0b, i0v);
    ff2f8(fi1a, fi1b, i1v);
    ff2f8(fmka, fmkb, mv);
#pragma unroll
    for (int j = 0; j < 8; ++j)
      av[j] = i0v[j] + mv[j] * ((i1v[j] - i0v[j]) - bs[j]);
    sth8(accP + (size_t)p * PLANE + erow, av);
    sth8(oS + (size_t)p * PLANE + erow, bs);
  } else if (MODE == M_MID) {
    float av[8], mv[8], D[8];
    q2f8(qacc, av);
    q2f8(qm, mv);
    q2f8(qd, D);
#pragma unroll
    for (int j = 0; j < 8; ++j) av[j] += mv[j] * (D[j] - bs[j]);
    sth8(accP + (size_t)p * PLANE + erow, av);
    sth8(oS + (size_t)p * PLANE + erow, bs);
  } else { // M_LAST: out = acc + Gm3*(D3 - D4) + Gm4*D4
    float av[8], m3[8], m4[8], D[8], o[8];
    q2f8(qacc, av);
    q2f8(qm, m3);
    q2f8(qm4, m4);
    q2f8(qd, D);
#pragma unroll
    for (int j = 0; j < 8; ++j)
      o[j] = av[j] + m3[j] * (D[j] - bs[j]) + m4[j] * bs[j];
    stf8(outp + (size_t)p * PLANE + erow, o);
  }
}

// ---------------- host -----------------------------------------------------
extern "C" void kernel_launch(void* const* d_in, const int* in_sizes, int n_in,
                              void* d_out, int out_size, void* d_ws,
                              size_t ws_size, hipStream_t stream) {
  const float* img0 = (const float*)d_in[0];
  const float* img1 = (const float*)d_in[1];
  const float* mask = (const float*)d_in[2];
  float* out = (float*)d_out;

  const int NTOT = 16;
  const size_t perImg = (size_t)11 * PLANE * sizeof(ushort);
  int CN = 16;
  while (CN > 1 && (size_t)CN * perImg > ws_size) CN >>= 1;

  for (int s = 0; s < NTOT; s += CN) {
    ushort* SA = (ushort*)d_ws; // [D:3CN][m:CN]
    ushort* SB = SA + (size_t)4 * CN * PLANE;
    ushort* acc = SB + (size_t)4 * CN * PLANE; // 3CN planes
    ushort* SAm = SA + (size_t)3 * CN * PLANE;
    ushort* SBm = SB + (size_t)3 * CN * PLANE;

    const float* in0 = img0 + (size_t)s * 3 * PLANE;
    const float* in1 = img1 + (size_t)s * 3 * PLANE;
    const float* inm = mask + (size_t)s * PLANE;
    float* o = out + (size_t)s * 3 * PLANE;

    const int cn3 = 3 * CN;
    const dim3 blk(512);
    const int gAll = 4 * CN * 64, gD = 3 * CN * 64, gM = CN * 64;
    const ushort* nb = nullptr;
    const float* nf = nullptr;

    // L0: acc = i0 + m*(D0-D1); SA.D = D1; SA.m = Gm1
    hipLaunchKernelGGL((fused_lvl<0, 6, M_F0>), dim3(gAll), blk, 0, stream, nb,
                       nb, nb, in0, in1, inm, SA, SAm, acc, (float*)nullptr,
                       cn3);
    // L1: acc += Gm1*(D1-D2); SB.D = D2; SB.m = Gm2
    hipLaunchKernelGGL((fused_lvl<1, 10, M_MID>), dim3(gAll), blk, 0, stream,
                       SA, SAm, nb, nf, nf, nf, SB, SBm, acc, (float*)nullptr,
                       cn3);
    // L2: acc += Gm2*(D2-D3); SA.D = D3; SA.m = Gm3
    hipLaunchKernelGGL((fused_lvl<2, 18, M_MID>), dim3(gAll), blk, 0, stream,
                       SB, SBm, nb, nf, nf, nf, SA, SAm, acc, (float*)nullptr,
                       cn3);
    // L3a: Gm4 = blur(Gm3) -> SB.m
    hipLaunchKernelGGL((fused_lvl<3, 22, M_MONLY>), dim3(gM), blk, 0, stream,
                       nb, SAm, nb, nf, nf, nf, (ushort*)nullptr, SBm,
                       (ushort*)nullptr, (float*)nullptr, cn3);
    // L3b: out = acc + Gm3*(D3-D4) + Gm4*D4
    hipLaunchKernelGGL((fused_lvl<3, 22, M_LAST>), dim3(gD), blk, 0, stream, SA,
                       SAm, SBm, nf, nf, nf, (ushort*)nullptr,
                       (ushort*)nullptr, acc, o, cn3);
  }
}

// Round 20
// 215.390 us; speedup vs baseline: 1.1723x; 1.0007x over previous
//
#include <hip/hip_runtime.h>

#define PH 512
#define PW 512
#define PLANE (PH * PW)

enum { M_F0 = 0, M_MID = 1, M_MONLY = 2, M_LAST = 3 };

// ---- compile-time Gaussian weights (literal constants in the ISA) ---------
constexpr double cexp_pos(double z) {
  double term = 1.0, sum = 1.0;
  for (int k = 1; k < 160; ++k) {
    term *= z / (double)k;
    sum += term;
  }
  return sum;
}
template <int LVL, int R>
struct WTab {
  float w[2 * R + 1];
  constexpr WTab() : w{} {
    double sig = 1.0;
    for (int i = 0; i < LVL; ++i) sig *= 2.0;
    double g[2 * R + 1] = {};
    double s = 0.0;
    for (int t = 0; t <= 2 * R; ++t) {
      double x = (double)(t - R);
      g[t] = 1.0 / cexp_pos((x * x) / (2.0 * sig * sig));
      s += g[t];
    }
    for (int t = 0; t <= 2 * R; ++t) w[t] = (float)(g[t] / s);
  }
};

__device__ __forceinline__ int clampi(int v, int hi) {
  return v < 0 ? 0 : (v > hi ? hi : v);
}
__device__ __forceinline__ int swz(int bid, int nwg) {
  const int q = nwg >> 3;
  return (bid & 7) * q + (bid >> 3);
}
union HU { ushort u; _Float16 h; };
union BU { uint4 q; ushort u[8]; };
__device__ __forceinline__ float h2f(ushort s) {
  HU x; x.u = s; return (float)x.h;
}
__device__ __forceinline__ ushort f2h(float f) {
  HU x; x.h = (_Float16)f; return x.u;
}
__device__ __forceinline__ void q2f8(uint4 q, float* v) {
  BU b; b.q = q;
#pragma unroll
  for (int j = 0; j < 8; ++j) v[j] = h2f(b.u[j]);
}
__device__ __forceinline__ void sth8(ushort* __restrict__ p, const float* v) {
  BU b;
#pragma unroll
  for (int j = 0; j < 8; ++j) b.u[j] = f2h(v[j]);
  *(uint4*)p = b.q;
}
__device__ __forceinline__ void ff2f8(float4 a, float4 b, float* v) {
  v[0] = a.x; v[1] = a.y; v[2] = a.z; v[3] = a.w;
  v[4] = b.x; v[5] = b.y; v[6] = b.z; v[7] = b.w;
}
__device__ __forceinline__ void stf8(float* __restrict__ p, const float* v) {
  *(float4*)p = make_float4(v[0], v[1], v[2], v[3]);
  *(float4*)(p + 4) = make_float4(v[4], v[5], v[6], v[7]);
}

// ---------------- fused per-level kernel, 64x64 tile, single LDS buffer ----
// R20 = exact R18 (the 215 us champion): R set {6,10,18,22} whose in-place
// H-conv schedule is validated on this compiler (R19 showed other R values
// reschedule the loop and race); D rides the epilogue global prefetch.
template <int LVL, int R, int MODE>
__global__ __launch_bounds__(512) void fused_lvl(
    const ushort* __restrict__ Sc, const ushort* __restrict__ Smk,
    const ushort* __restrict__ Gm4p, const float* __restrict__ in0,
    const float* __restrict__ in1, const float* __restrict__ inm,
    ushort* __restrict__ oS, ushort* __restrict__ oM,
    ushort* __restrict__ accP, float* __restrict__ outp, int cn3) {
  constexpr WTab<LVL, R> WT;
  constexpr int R8 = ((R + 7) / 8) * 8; // 8,16,24,24
  constexpr int WW = 64 + 2 * R8;       // 80,96,112,112
  constexpr int WSTR = WW + 6;          // == 6 mod 8 -> b64 reads <=2-way
  constexpr int VWIN = 64 + 2 * R;      // 76,84,100,108
  constexpr int NCH = WW / 8;
  constexpr int NJOBS = VWIN * NCH;
  constexpr int NHJ = VWIN * 8;
  __shared__ float Wb[VWIN * WSTR];

  const int bid = swz(blockIdx.x, gridDim.x);
  const int tid = threadIdx.x;
  const int p = bid >> 6, t = bid & 63;
  const int tx = t & 7;
  const int x0 = tx << 6, y0 = (t >> 3) << 6;
  const bool edge = (tx == 0) || (tx == 7);
  const int ey = tid >> 3, exq = (tid & 7) << 3;
  const size_t erow = (size_t)(y0 + ey) * PW + x0 + exq;

  const bool ismask = (MODE == M_MONLY) || (MODE != M_LAST && p >= cn3);
  const int pm = ismask ? ((MODE == M_MONLY) ? p : p - cn3) : 0;
  const int n = p / 3;

  // ---- prefetch pointwise epilogue streams incl. the D source ----
  uint4 qacc{}, qm{}, qm4{}, qd{};
  float4 fi0a{}, fi0b{}, fi1a{}, fi1b{}, fmka{}, fmkb{};
  if (!ismask) {
    if (MODE == M_F0) {
      const float* p0 = in0 + (size_t)p * PLANE + erow;
      fi0a = ((const float4*)p0)[0];
      fi0b = ((const float4*)p0)[1];
      const float* p1 = in1 + (size_t)p * PLANE + erow;
      fi1a = ((const float4*)p1)[0];
      fi1b = ((const float4*)p1)[1];
      const float* pk = inm + (size_t)n * PLANE + erow;
      fmka = ((const float4*)pk)[0];
      fmkb = ((const float4*)pk)[1];
    } else {
      qacc = *(const uint4*)(accP + (size_t)p * PLANE + erow);
      qm = *(const uint4*)(Smk + (size_t)n * PLANE + erow);
      qd = *(const uint4*)(Sc + (size_t)p * PLANE + erow);
      if (MODE == M_LAST)
        qm4 = *(const uint4*)(Gm4p + (size_t)n * PLANE + erow);
    }
  }

  // ---- fill Wb: job = (row, ch8); rows y-clamped, cols x-clamped ----
  for (int j0 = tid; j0 < NJOBS; j0 += 512) {
    const int row = j0 / NCH, ch = j0 % NCH;
    const int gy = clampi(y0 + row - R, PH - 1);
    const int gx = x0 - R8 + (ch << 3);
    float v[8];
    if (MODE == M_F0) {
      if (!ismask) {
        const float* r0 = in0 + (size_t)p * PLANE + (size_t)gy * PW;
        const float* r1 = in1 + (size_t)p * PLANE + (size_t)gy * PW;
        if (!edge || (gx >= 0 && gx <= PW - 8)) {
          float a[8], bb[8];
          ff2f8(((const float4*)(r0 + gx))[0], ((const float4*)(r0 + gx))[1], a);
          ff2f8(((const float4*)(r1 + gx))[0], ((const float4*)(r1 + gx))[1], bb);
#pragma unroll
          for (int j = 0; j < 8; ++j) v[j] = bb[j] - a[j];
        } else {
#pragma unroll
          for (int j = 0; j < 8; ++j) {
            const int cx = clampi(gx + j, PW - 1);
            v[j] = r1[cx] - r0[cx];
          }
        }
      } else {
        const float* rm = inm + (size_t)pm * PLANE + (size_t)gy * PW;
        if (!edge || (gx >= 0 && gx <= PW - 8)) {
          ff2f8(((const float4*)(rm + gx))[0], ((const float4*)(rm + gx))[1], v);
        } else {
#pragma unroll
          for (int j = 0; j < 8; ++j) v[j] = rm[clampi(gx + j, PW - 1)];
        }
      }
    } else {
      const ushort* sp =
          (ismask ? Smk + (size_t)pm * PLANE : Sc + (size_t)p * PLANE) +
          (size_t)gy * PW;
      if (!edge || (gx >= 0 && gx <= PW - 8)) {
        q2f8(*(const uint4*)&sp[gx], v);
      } else {
#pragma unroll
        for (int j = 0; j < 8; ++j) v[j] = h2f(sp[clampi(gx + j, PW - 1)]);
      }
    }
    float* d = &Wb[row * WSTR + (ch << 3)];
#pragma unroll
    for (int k = 0; k < 4; ++k)
      *(float2*)&d[2 * k] = make_float2(v[2 * k], v[2 * k + 1]);
  }
  __syncthreads();

  // ---- H conv IN PLACE: job (r,cg) reads row r window, writes cols cg*8 ----
  // (identical loop body to R12/R13/R16/R18 -> identical validated schedule)
#pragma unroll
  for (int i = 0; i < (NHJ + 511) / 512; ++i) {
    const int j0 = tid + (i << 9);
    if (j0 < NHJ) {
      const int r = j0 >> 3, cg = j0 & 7;
      constexpr int basep = R8 - R;
      const float* wr = &Wb[r * WSTR + basep + (cg << 3)];
      float a[8];
#pragma unroll
      for (int i2 = 0; i2 < 8; ++i2) a[i2] = 0.f;
#pragma unroll
      for (int j2 = 0; j2 < R + 4; ++j2) {
        const float2 v2 = *(const float2*)&wr[2 * j2];
        const int j0e = 2 * j2, j1e = 2 * j2 + 1;
#pragma unroll
        for (int i2 = 0; i2 < 8; ++i2) {
          if (i2 <= j0e && j0e - i2 <= 2 * R)
            a[i2] = fmaf(WT.w[j0e - i2], v2.x, a[i2]);
          if (i2 <= j1e && j1e - i2 <= 2 * R)
            a[i2] = fmaf(WT.w[j1e - i2], v2.y, a[i2]);
        }
      }
      float* hr = &Wb[r * WSTR + (cg << 3)];
#pragma unroll
      for (int k2 = 0; k2 < 4; ++k2)
        *(float2*)&hr[2 * k2] = make_float2(a[2 * k2], a[2 * k2 + 1]);
    }
  }
  __syncthreads();

  // ---- V conv: 8 consecutive rows at column `lane` ----
  const int lane = tid & 63, yg = tid >> 6;
  float b[8];
#pragma unroll
  for (int i = 0; i < 8; ++i) b[i] = 0.f;
#pragma unroll
  for (int j = 0; j < 2 * R + 8; ++j) {
    const float v = Wb[((yg << 3) + j) * WSTR + lane];
#pragma unroll
    for (int i = 0; i < 8; ++i)
      if (i <= j && j - i <= 2 * R) b[i] = fmaf(WT.w[j - i], v, b[i]);
  }
  __syncthreads(); // V reads done -> Wb reusable as transpose stash

#pragma unroll
  for (int i = 0; i < 8; ++i) Wb[lane * 65 + (yg << 3) + i] = b[i];
  __syncthreads();
  float bs[8];
#pragma unroll
  for (int j = 0; j < 8; ++j) bs[j] = Wb[(exq + j) * 65 + ey];

  if (ismask) {
    sth8(oM + (size_t)pm * PLANE + erow, bs);
    return;
  }

  if (MODE == M_F0) {
    float i0v[8], i1v[8], mv[8], av[8];
    ff2f8(fi0a, fi0b, i0v);
    ff2f8(fi1a, fi1b, i1v);
    ff2f8(fmka, fmkb, mv);
#pragma unroll
    for (int j = 0; j < 8; ++j)
      av[j] = i0v[j] + mv[j] * ((i1v[j] - i0v[j]) - bs[j]);
    sth8(accP + (size_t)p * PLANE + erow, av);
    sth8(oS + (size_t)p * PLANE + erow, bs);
  } else if (MODE == M_MID) {
    float av[8], mv[8], D[8];
    q2f8(qacc, av);
    q2f8(qm, mv);
    q2f8(qd, D);
#pragma unroll
    for (int j = 0; j < 8; ++j) av[j] += mv[j] * (D[j] - bs[j]);
    sth8(accP + (size_t)p * PLANE + erow, av);
    sth8(oS + (size_t)p * PLANE + erow, bs);
  } else { // M_LAST: out = acc + Gm3*(D3 - D4) + Gm4*D4
    float av[8], m3[8], m4[8], D[8], o[8];
    q2f8(qacc, av);
    q2f8(qm, m3);
    q2f8(qm4, m4);
    q2f8(qd, D);
#pragma unroll
    for (int j = 0; j < 8; ++j)
      o[j] = av[j] + m3[j] * (D[j] - bs[j]) + m4[j] * bs[j];
    stf8(outp + (size_t)p * PLANE + erow, o);
  }
}

// ---------------- host -----------------------------------------------------
extern "C" void kernel_launch(void* const* d_in, const int* in_sizes, int n_in,
                              void* d_out, int out_size, void* d_ws,
                              size_t ws_size, hipStream_t stream) {
  const float* img0 = (const float*)d_in[0];
  const float* img1 = (const float*)d_in[1];
  const float* mask = (const float*)d_in[2];
  float* out = (float*)d_out;

  const int NTOT = 16;
  const size_t perImg = (size_t)11 * PLANE * sizeof(ushort);
  int CN = 16;
  while (CN > 1 && (size_t)CN * perImg > ws_size) CN >>= 1;

  for (int s = 0; s < NTOT; s += CN) {
    ushort* SA = (ushort*)d_ws; // [D:3CN][m:CN]
    ushort* SB = SA + (size_t)4 * CN * PLANE;
    ushort* acc = SB + (size_t)4 * CN * PLANE; // 3CN planes
    ushort* SAm = SA + (size_t)3 * CN * PLANE;
    ushort* SBm = SB + (size_t)3 * CN * PLANE;

    const float* in0 = img0 + (size_t)s * 3 * PLANE;
    const float* in1 = img1 + (size_t)s * 3 * PLANE;
    const float* inm = mask + (size_t)s * PLANE;
    float* o = out + (size_t)s * 3 * PLANE;

    const int cn3 = 3 * CN;
    const dim3 blk(512);
    const int gAll = 4 * CN * 64, gD = 3 * CN * 64, gM = CN * 64;
    const ushort* nb = nullptr;
    const float* nf = nullptr;

    // L0: acc = i0 + m*(D0-D1); SA.D = D1; SA.m = Gm1
    hipLaunchKernelGGL((fused_lvl<0, 6, M_F0>), dim3(gAll), blk, 0, stream, nb,
                       nb, nb, in0, in1, inm, SA, SAm, acc, (float*)nullptr,
                       cn3);
    // L1: acc += Gm1*(D1-D2); SB.D = D2; SB.m = Gm2
    hipLaunchKernelGGL((fused_lvl<1, 10, M_MID>), dim3(gAll), blk, 0, stream,
                       SA, SAm, nb, nf, nf, nf, SB, SBm, acc, (float*)nullptr,
                       cn3);
    // L2: acc += Gm2*(D2-D3); SA.D = D3; SA.m = Gm3
    hipLaunchKernelGGL((fused_lvl<2, 18, M_MID>), dim3(gAll), blk, 0, stream,
                       SB, SBm, nb, nf, nf, nf, SA, SAm, acc, (float*)nullptr,
                       cn3);
    // L3a: Gm4 = blur(Gm3) -> SB.m
    hipLaunchKernelGGL((fused_lvl<3, 22, M_MONLY>), dim3(gM), blk, 0, stream,
                       nb, SAm, nb, nf, nf, nf, (ushort*)nullptr, SBm,
                       (ushort*)nullptr, (float*)nullptr, cn3);
    // L3b: out = acc + Gm3*(D3-D4) + Gm4*D4
    hipLaunchKernelGGL((fused_lvl<3, 22, M_LAST>), dim3(gD), blk, 0, stream, SA,
                       SAm, SBm, nf, nf, nf, (ushort*)nullptr,
                       (ushort*)nullptr, acc, o, cn3);
  }
}